// Round 1
// baseline (212.268 us; speedup 1.0000x reference)
//
#include <hip/hip_runtime.h>
#include <math.h>

#define D_BINS 59
#define CO     64
#define CI     256
#define NB     4
#define NC     6
#define H_IMG  16
#define W_IMG  44
#define HW     704            // H_IMG * W_IMG
#define NPIX   (NB*NC*HW)     // 16896
#define XD     128
#define YD     128
#define ZD     7
#define NOUT   123            // D_BINS + CO
#define PXB    66             // pixels per k_head block: 256 * 66 == NPIX exactly

typedef float v2f __attribute__((ext_vector_type(2)));

// ---------------------------------------------------------------------------
// Double-precision rigid-transform inverse (matches np.linalg.inv to ~1e-15,
// avoiding depth-bin boundary flips downstream).
// ---------------------------------------------------------------------------
__device__ void inv_rigid(const float* __restrict__ M, float* __restrict__ o) {
    double a = M[0], b = M[1], c = M[2], t0 = M[3];
    double d = M[4], e = M[5], f = M[6], t1 = M[7];
    double g = M[8], h = M[9], ii = M[10], t2 = M[11];
    double A00 = e*ii - f*h, A01 = c*h - b*ii, A02 = b*f - c*e;
    double A10 = f*g - d*ii, A11 = a*ii - c*g, A12 = c*d - a*f;
    double A20 = d*h - e*g,  A21 = b*g - a*h,  A22 = a*e - b*d;
    double det = a*A00 + b*A10 + c*A20;
    double inv = 1.0 / det;
    double r00 = A00*inv, r01 = A01*inv, r02 = A02*inv;
    double r10 = A10*inv, r11 = A11*inv, r12 = A12*inv;
    double r20 = A20*inv, r21 = A21*inv, r22 = A22*inv;
    o[0] = (float)r00; o[1] = (float)r01; o[2]  = (float)r02;
    o[3] = (float)(-(r00*t0 + r01*t1 + r02*t2));
    o[4] = (float)r10; o[5] = (float)r11; o[6]  = (float)r12;
    o[7] = (float)(-(r10*t0 + r11*t1 + r12*t2));
    o[8] = (float)r20; o[9] = (float)r21; o[10] = (float)r22;
    o[11] = (float)(-(r20*t0 + r21*t1 + r22*t2));
}

// ---------------------------------------------------------------------------
// Kernel 1: prep. W (123x256) -> wt2, k-pair-interleaved + transposed.
// Unchanged.
// ---------------------------------------------------------------------------
__global__ __launch_bounds__(256) void k_pre(
    const float* __restrict__ wd, const float* __restrict__ c2e,
    float* __restrict__ wt2, float* __restrict__ e2c) {
    const int o = blockIdx.x;   // 0..127
    const int k = threadIdx.x;  // 0..255
    float v = (o < NOUT) ? wd[(size_t)o * CI + k] : 0.f;
    wt2[(size_t)(k >> 1) * 256 + o * 2 + (k & 1)] = v;
    if (blockIdx.x == 0 && k < NB * NC)
        inv_rigid(c2e + k * 16, e2c + k * 12);
}

// ---------------------------------------------------------------------------
// Kernel 2: depth/feat head. Unchanged from the 124 µs version.
// ---------------------------------------------------------------------------
__global__ __launch_bounds__(640) void k_head(
    const float* __restrict__ img, const float* __restrict__ wt2,
    const float* __restrict__ bd, float* __restrict__ depth_out,
    float* __restrict__ feat_ws) {
    __shared__ float smem[PXB * 132 + PXB];
    float* S = smem + PXB * 132;

    const int tid = threadIdx.x;
    const int wv  = tid >> 6;            // 0..9
    const int ln  = tid & 63;
    const int p0  = blockIdx.x * PXB;
    const bool is_main = (wv < 8);
    const int o0  = __builtin_amdgcn_readfirstlane((is_main ? wv : 0) << 4);
    const int epx = 64 + (wv - 8);

    v2f acc[16];
#pragma unroll
    for (int j = 0; j < 16; ++j) acc[j] = (v2f)(0.f);
    v2f acc2a = (v2f)(0.f), acc2b = (v2f)(0.f);

    for (int kc = 0; kc < 4; ++kc) {
#pragma unroll
        for (int it = 0; it < 7; ++it) {
            int idx = tid + it * 640;
            if (idx < 64 * PXB) {
                int kl = idx / PXB, px = idx - kl * PXB;
                int p = p0 + px;
                int bn = p / HW, hw = p - bn * HW;
                smem[(kl >> 1) * 132 + px * 2 + (kl & 1)] =
                    img[((size_t)bn * CI + kc * 64 + kl) * HW + hw];
            }
        }
        __syncthreads();
        if (is_main) {
#pragma unroll 4
            for (int k2 = 0; k2 < 32; ++k2) {
                v2f a = *(const v2f*)(smem + k2 * 132 + ln * 2);
                const v2f* w =
                    (const v2f*)(wt2 + (size_t)(kc * 32 + k2) * 256) + o0;
#pragma unroll
                for (int j = 0; j < 16; ++j)
                    acc[j] = __builtin_elementwise_fma(a, w[j], acc[j]);
            }
        } else {
#pragma unroll 4
            for (int k2 = 0; k2 < 32; ++k2) {
                v2f a = *(const v2f*)(smem + k2 * 132 + epx * 2);
                const float* w = wt2 + (size_t)(kc * 32 + k2) * 256;
                v2f w0 = {w[ln * 2], w[ln * 2 + 1]};
                v2f w1 = {w[(ln + 64) * 2], w[(ln + 64) * 2 + 1]};
                acc2a = __builtin_elementwise_fma(a, w0, acc2a);
                acc2b = __builtin_elementwise_fma(a, w1, acc2b);
            }
        }
        __syncthreads();
    }

    float* X = smem;
    if (is_main) {
#pragma unroll
        for (int j = 0; j < 16; ++j) {
            int o = o0 + j;
            if (o < NOUT) {
                int col = (o < D_BINS) ? o : o + 5;
                X[ln * 132 + col] = (acc[j].x + acc[j].y) + bd[o];
            }
        }
    } else {
        int o = ln;
        X[epx * 132 + ((o < D_BINS) ? o : o + 5)] = (acc2a.x + acc2a.y) + bd[o];
        o = ln + 64;
        if (o < NOUT)
            X[epx * 132 + ((o < D_BINS) ? o : o + 5)] = (acc2b.x + acc2b.y) + bd[o];
    }
    __syncthreads();

#pragma unroll
    for (int it = 0; it < 2; ++it) {
        int g = tid + it * 640;
        if (g < PXB * 16) {
            int p = g >> 4, m = g & 15;
            float4 v = *(const float4*)(X + p * 132 + 64 + m * 4);
            *(float4*)(feat_ws + (size_t)(p0 + p) * CO + m * 4) = v;
        }
    }

    if (tid < PXB) {
        float* row = X + tid * 132;
        float m = row[0];
        for (int o = 1; o < D_BINS; ++o) m = fmaxf(m, row[o]);
        float s = 0.f;
        for (int o = 0; o < D_BINS; ++o) {
            float e = __expf(row[o] - m);
            row[o] = e;
            s += e;
        }
        S[tid] = 1.f / s;
    }
    __syncthreads();

    for (int g = tid; g < PXB * D_BINS; g += 640) {
        int p = g / D_BINS;
        int o = g - p * D_BINS;
        depth_out[(size_t)p0 * D_BINS + g] = X[p * 132 + o] * S[p];
    }
}

// ---------------------------------------------------------------------------
// Kernel 3: project voxels, gather depth weight + feat, splat to BEV.
// RESTRUCTURED accumulate phase: lane = channel (0..63), wave owns 16
// x-columns. Per (x,z,n) sample: hw/wgt are wave-uniform (readfirstlane ->
// scalar branch, zero divergence) and the feat gather is ONE coalesced
// 256B global_load_dword (saddr) instead of 4 x 64-lane-scattered dwordx4
// (was ~64 distinct 64B lines per instruction, 16B used each -> TA-bound).
// Loads batched 2 x-columns x 7 z deep before the FMA block so up to 14
// loads are in flight per wave. Projection float expressions and per-(x,c)
// FMA order (n outer, z ascending) identical to the 124 µs version ->
// numerically identical (invalid slots add fmaf(0,0,acc), exact).
// Output transposed through padded LDS tile -> bev stores stay coalesced.
// ---------------------------------------------------------------------------
__global__ __launch_bounds__(256) void k_splat(
    const float* __restrict__ e2c, const float* __restrict__ Kmat,
    const float* __restrict__ depth_g, const float* __restrict__ feat_ws,
    float* __restrict__ bev) {
    __shared__ int2  proj_s[ZD][64];   // {hw, bitcast(wgt)} per (z, x)
    __shared__ float out_s[64][65];    // [c][x], +1 pad

    const int tx = threadIdx.x;        // 0..63: projection x / accumulate c
    const int ty = threadIdx.y;        // 0..3 : projection z-group / wave id
    const int tid = ty * 64 + tx;
    const int x0 = blockIdx.x * 64;
    const int y  = blockIdx.y;
    const int b  = blockIdx.z;

    const int c  = tx;                 // accumulate: lane = channel
    const int wvx = ty * 16;           // this wave's first x column

    const float wx = (float)(x0 + tx) * 0.8f + (-51.2f);
    const float wy = (float)y * 0.8f + (-51.2f);

    float acc[16];
#pragma unroll
    for (int m = 0; m < 16; ++m) acc[m] = 0.f;

    for (int n = 0; n < NC; ++n) {
        const int bn = b * NC + n;
        const size_t bnHW = (size_t)bn * HW;

        // ---- projection phase: thread (tx,ty) owns z = ty and ty+4 ----
        {
            const float* E = e2c + bn * 12;
            const float* Km = Kmat + bn * 9;
            const float k00 = Km[0], k01 = Km[1], k02 = Km[2];
            const float k10 = Km[3], k11 = Km[4], k12 = Km[5];
            const float e02 = E[2], e12 = E[6], e22 = E[10];
            const float bx0 = E[0] * wx + E[1] * wy + E[3];
            const float bx1 = E[4] * wx + E[5] * wy + E[7];
            const float bx2 = E[8] * wx + E[9] * wy + E[11];
#pragma unroll
            for (int zz = 0; zz < 2; ++zz) {
                const int z = ty + zz * 4;
                if (z < ZD) {
                    const float wz = -2.5f + (float)z;
                    const float cx = bx0 + e02 * wz;
                    const float cy = bx1 + e12 * wz;
                    const float cz = bx2 + e22 * wz;
                    const float zs = fmaxf(cz, 0.1f);
                    const float rz = 1.0f / zs;         // IEEE divide
                    const float xn = cx * rz;
                    const float yn = cy * rz;
                    const float fu = (k00 * xn + k01 * yn + k02) * 0.0625f;
                    const float fv = (k10 * xn + k11 * yn + k12) * 0.0625f;
                    const int bin = (int)(cz - 1.0f);   // trunc, = astype(int32)
                    const bool valid = (fu >= 0.f) & (fu < (float)W_IMG) &
                                       (fv >= 0.f) & (fv < (float)H_IMG) &
                                       (cz > 0.5f) & (bin >= 0) & (bin < D_BINS);
                    int hw = -1;
                    float wgt = 0.f;
                    if (valid) {
                        int u = (int)fu;                // valid => in range
                        int v = (int)fv;
                        hw = v * W_IMG + u;
                        wgt = depth_g[(bnHW + hw) * D_BINS + bin];
                    }
                    proj_s[z][tx] = make_int2(hw, __float_as_int(wgt));
                }
            }
        }
        __syncthreads();

        // ---- accumulate: wave-uniform hw/wgt, coalesced feat loads ----
#pragma unroll
        for (int xp = 0; xp < 8; ++xp) {
            const int xl0 = wvx + xp * 2;
            const int xl1 = xl0 + 1;
            float fv0[ZD], fw0[ZD], fv1[ZD], fw1[ZD];
#pragma unroll
            for (int z = 0; z < ZD; ++z) {
                int2 p0 = proj_s[z][xl0];               // LDS broadcast
                int hw0 = __builtin_amdgcn_readfirstlane(p0.x);
                if (hw0 >= 0) {                          // scalar branch
                    fw0[z] = __int_as_float(__builtin_amdgcn_readfirstlane(p0.y));
                    fv0[z] = feat_ws[(bnHW + (size_t)hw0) * CO + c];
                } else { fw0[z] = 0.f; fv0[z] = 0.f; }
                int2 p1 = proj_s[z][xl1];
                int hw1 = __builtin_amdgcn_readfirstlane(p1.x);
                if (hw1 >= 0) {
                    fw1[z] = __int_as_float(__builtin_amdgcn_readfirstlane(p1.y));
                    fv1[z] = feat_ws[(bnHW + (size_t)hw1) * CO + c];
                } else { fw1[z] = 0.f; fv1[z] = 0.f; }
            }
#pragma unroll
            for (int z = 0; z < ZD; ++z) {              // z ascending, n outer
                acc[xp * 2]     = fmaf(fw0[z], fv0[z], acc[xp * 2]);
                acc[xp * 2 + 1] = fmaf(fw1[z], fv1[z], acc[xp * 2 + 1]);
            }
        }
        __syncthreads();   // proj_s reused next n
    }

    // ---- transpose via LDS, coalesced bev stores ----
#pragma unroll
    for (int xi = 0; xi < 16; ++xi)
        out_s[c][wvx + xi] = acc[xi];   // banks (c+x)%32: 2-way = free
    __syncthreads();

    for (int g = tid; g < 64 * 64; g += 256) {
        int cc = g >> 6, xx = g & 63;   // cc wave-uniform, xx = lane
        bev[(((size_t)b * CO + cc) * YD + y) * XD + x0 + xx] = out_s[cc][xx];
    }
}

extern "C" void kernel_launch(void* const* d_in, const int* in_sizes, int n_in,
                              void* d_out, int out_size, void* d_ws, size_t ws_size,
                              hipStream_t stream) {
    const float* img  = (const float*)d_in[0];  // (B,N,256,16,44)
    const float* c2e  = (const float*)d_in[1];  // (B,N,4,4)
    const float* Kmat = (const float*)d_in[2];  // (B,N,3,3)
    const float* wd   = (const float*)d_in[3];  // (123,256)
    const float* bd   = (const float*)d_in[4];  // (123,)
    float* bev = (float*)d_out;                         // (B,64,128,128)
    float* depth_out = bev + (size_t)NB * CO * YD * XD; // (B,N,16,44,59)
    float* feat_ws = (float*)d_ws;                      // NPIX*64 floats
    float* wt2 = feat_ws + (size_t)NPIX * CO;           // 128*256 floats
    float* e2c = wt2 + 128 * 256;                       // 24*12 floats

    k_pre<<<128, 256, 0, stream>>>(wd, c2e, wt2, e2c);
    k_head<<<256, 640, 0, stream>>>(img, wt2, bd, depth_out, feat_ws);
    k_splat<<<dim3(2, YD, NB), dim3(64, 4, 1), 0, stream>>>(e2c, Kmat, depth_out,
                                                            feat_ws, bev);
}

// Round 2
// 124.218 us; speedup vs baseline: 1.7088x; 1.7088x over previous
//
#include <hip/hip_runtime.h>
#include <math.h>

#define D_BINS 59
#define CO     64
#define CI     256
#define NB     4
#define NC     6
#define H_IMG  16
#define W_IMG  44
#define HW     704            // H_IMG * W_IMG
#define NPIX   (NB*NC*HW)     // 16896
#define XD     128
#define YD     128
#define ZD     7
#define NOUT   123            // D_BINS + CO
#define PXB    66             // pixels per k_head block: 256 * 66 == NPIX exactly
#define ABUF   4224           // one A chunk: 32 kp rows x 132 floats

typedef float v2f __attribute__((ext_vector_type(2)));

// ---------------------------------------------------------------------------
// Double-precision rigid-transform inverse (matches np.linalg.inv to ~1e-15,
// avoiding depth-bin boundary flips downstream).
// ---------------------------------------------------------------------------
__device__ void inv_rigid(const float* __restrict__ M, float* __restrict__ o) {
    double a = M[0], b = M[1], c = M[2], t0 = M[3];
    double d = M[4], e = M[5], f = M[6], t1 = M[7];
    double g = M[8], h = M[9], ii = M[10], t2 = M[11];
    double A00 = e*ii - f*h, A01 = c*h - b*ii, A02 = b*f - c*e;
    double A10 = f*g - d*ii, A11 = a*ii - c*g, A12 = c*d - a*f;
    double A20 = d*h - e*g,  A21 = b*g - a*h,  A22 = a*e - b*d;
    double det = a*A00 + b*A10 + c*A20;
    double inv = 1.0 / det;
    double r00 = A00*inv, r01 = A01*inv, r02 = A02*inv;
    double r10 = A10*inv, r11 = A11*inv, r12 = A12*inv;
    double r20 = A20*inv, r21 = A21*inv, r22 = A22*inv;
    o[0] = (float)r00; o[1] = (float)r01; o[2]  = (float)r02;
    o[3] = (float)(-(r00*t0 + r01*t1 + r02*t2));
    o[4] = (float)r10; o[5] = (float)r11; o[6]  = (float)r12;
    o[7] = (float)(-(r10*t0 + r11*t1 + r12*t2));
    o[8] = (float)r20; o[9] = (float)r21; o[10] = (float)r22;
    o[11] = (float)(-(r20*t0 + r21*t1 + r22*t2));
}

// ---------------------------------------------------------------------------
// Kernel 1: prep. W (123x256) -> wt2, k-pair-interleaved + transposed.
// Unchanged.
// ---------------------------------------------------------------------------
__global__ __launch_bounds__(256) void k_pre(
    const float* __restrict__ wd, const float* __restrict__ c2e,
    float* __restrict__ wt2, float* __restrict__ e2c) {
    const int o = blockIdx.x;   // 0..127
    const int k = threadIdx.x;  // 0..255
    float v = (o < NOUT) ? wd[(size_t)o * CI + k] : 0.f;
    wt2[(size_t)(k >> 1) * 256 + o * 2 + (k & 1)] = v;
    if (blockIdx.x == 0 && k < NB * NC)
        inv_rigid(c2e + k * 16, e2c + k * 12);
}

// ---------------------------------------------------------------------------
// Kernel 2: depth/feat head. NEW this round (T14 async-STAGE + dbuf):
//  - staging addresses (div/mod 66) precomputed ONCE outside the kc loop
//  - A is double-buffered (2 x 4224 floats, both inside the X region):
//    issue next chunk's 7 global loads to REGISTERS before compute,
//    compute current chunk, then ds_write regs -> other buffer.
//    One __syncthreads() per chunk (was two); HBM latency hides under the
//    2048 v_pk_fma_f32 of the compute phase (1 block/CU -> no TLP to rely on).
// GEMM core, epilogue, softmax unchanged.
// ---------------------------------------------------------------------------
__global__ __launch_bounds__(640) void k_head(
    const float* __restrict__ img, const float* __restrict__ wt2,
    const float* __restrict__ bd, float* __restrict__ depth_out,
    float* __restrict__ feat_ws) {
    __shared__ float smem[PXB * 132 + PXB];  // A dbuf (2x4224) aliases X region
    float* S = smem + PXB * 132;

    const int tid = threadIdx.x;
    const int wv  = tid >> 6;            // 0..9
    const int ln  = tid & 63;
    const int p0  = blockIdx.x * PXB;
    const bool is_main = (wv < 8);
    const int o0  = __builtin_amdgcn_readfirstlane((is_main ? wv : 0) << 4);
    const int epx = 64 + (wv - 8);       // edge wave's pixel column (64 or 65)

    // ---- staging address precompute (kc-invariant) ----
    int a_off[7];   // LDS offset within an A buffer, -1 = inactive
    int g_off[7];   // img element offset for kc=0 (add kc*64*HW)
#pragma unroll
    for (int it = 0; it < 7; ++it) {
        int idx = tid + it * 640;
        if (idx < 64 * PXB) {
            int kl = idx / PXB, px = idx - kl * PXB;
            int p = p0 + px;
            int bn = p / HW, hw = p - bn * HW;
            a_off[it] = (kl >> 1) * 132 + px * 2 + (kl & 1);
            g_off[it] = (bn * CI + kl) * HW + hw;
        } else {
            a_off[it] = -1;
            g_off[it] = 0;
        }
    }

    v2f acc[16];                          // [o-within-strip] = {even-k, odd-k}
#pragma unroll
    for (int j = 0; j < 16; ++j) acc[j] = (v2f)(0.f);
    v2f acc2a = (v2f)(0.f), acc2b = (v2f)(0.f);

    // prologue: stage chunk 0 into buf0
#pragma unroll
    for (int it = 0; it < 7; ++it)
        if (a_off[it] >= 0) smem[a_off[it]] = img[g_off[it]];
    __syncthreads();

    for (int kc = 0; kc < 4; ++kc) {
        const float* A = smem + (kc & 1) * ABUF;
        float* An = smem + ((kc + 1) & 1) * ABUF;

        // issue next chunk's loads early (results consumed after compute)
        float r[7];
        if (kc < 3) {
#pragma unroll
            for (int it = 0; it < 7; ++it)
                if (a_off[it] >= 0)
                    r[it] = img[g_off[it] + (kc + 1) * 64 * HW];
        }

        if (is_main) {
#pragma unroll 4
            for (int k2 = 0; k2 < 32; ++k2) {
                v2f a = *(const v2f*)(A + k2 * 132 + ln * 2);  // stride-8B: free
                const v2f* w =
                    (const v2f*)(wt2 + (size_t)(kc * 32 + k2) * 256) + o0; // uniform
#pragma unroll
                for (int j = 0; j < 16; ++j)
                    acc[j] = __builtin_elementwise_fma(a, w[j], acc[j]);
            }
        } else {
#pragma unroll 4
            for (int k2 = 0; k2 < 32; ++k2) {
                v2f a = *(const v2f*)(A + k2 * 132 + epx * 2);  // broadcast
                const float* w = wt2 + (size_t)(kc * 32 + k2) * 256;
                v2f w0 = {w[ln * 2], w[ln * 2 + 1]};
                v2f w1 = {w[(ln + 64) * 2], w[(ln + 64) * 2 + 1]};
                acc2a = __builtin_elementwise_fma(a, w0, acc2a);
                acc2b = __builtin_elementwise_fma(a, w1, acc2b);
            }
        }

        // write-late: staged regs -> alternate buffer, then one barrier
        if (kc < 3) {
#pragma unroll
            for (int it = 0; it < 7; ++it)
                if (a_off[it] >= 0) An[a_off[it]] = r[it];
        }
        __syncthreads();
    }

    // epilogue into X[66][132]: logits at col o (<59), feat at col o+5 (64..127)
    float* X = smem;
    if (is_main) {
#pragma unroll
        for (int j = 0; j < 16; ++j) {
            int o = o0 + j;
            if (o < NOUT) {
                int col = (o < D_BINS) ? o : o + 5;
                X[ln * 132 + col] = (acc[j].x + acc[j].y) + bd[o];
            }
        }
    } else {
        int o = ln;
        X[epx * 132 + ((o < D_BINS) ? o : o + 5)] = (acc2a.x + acc2a.y) + bd[o];
        o = ln + 64;
        if (o < NOUT)
            X[epx * 132 + ((o < D_BINS) ? o : o + 5)] = (acc2b.x + acc2b.y) + bd[o];
    }
    __syncthreads();

    // feat: X[p][64..127] -> feat_ws[(p0+p)*64 ...], coalesced float4
#pragma unroll
    for (int it = 0; it < 2; ++it) {
        int g = tid + it * 640;            // 66*16 = 1056 float4s
        if (g < PXB * 16) {
            int p = g >> 4, m = g & 15;
            float4 v = *(const float4*)(X + p * 132 + 64 + m * 4);
            *(float4*)(feat_ws + (size_t)(p0 + p) * CO + m * 4) = v;
        }
    }

    // softmax over cols 0..58, one thread per pixel
    if (tid < PXB) {
        float* row = X + tid * 132;
        float m = row[0];
        for (int o = 1; o < D_BINS; ++o) m = fmaxf(m, row[o]);
        float s = 0.f;
        for (int o = 0; o < D_BINS; ++o) {
            float e = __expf(row[o] - m);
            row[o] = e;
            s += e;
        }
        S[tid] = 1.f / s;
    }
    __syncthreads();

    // depth: block region contiguous [p0*59, (p0+66)*59) -> coalesced
    for (int g = tid; g < PXB * D_BINS; g += 640) {
        int p = g / D_BINS;
        int o = g - p * D_BINS;
        depth_out[(size_t)p0 * D_BINS + g] = X[p * 132 + o] * S[p];
    }
}

// ---------------------------------------------------------------------------
// Kernel 3: project voxels, gather depth weight + feat, splat to BEV.
// REVERTED verbatim to the round-0 (124 µs baseline) version: per camera n,
// a projection phase computes each (x,z) sample's {hw, depth-weight} ONCE
// into LDS; the accumulate phase broadcasts them to all 4 channel-quarter
// threads which do only their feat gathers + FMAs. (The lane=channel
// restructure was 2.7x slower: LDS->readfirstlane->branch serial chain per
// sample, latency-bound at 22% occupancy.)
// ---------------------------------------------------------------------------
__global__ __launch_bounds__(256) void k_splat(
    const float* __restrict__ e2c, const float* __restrict__ Kmat,
    const float* __restrict__ depth_g, const float* __restrict__ feat_ws,
    float* __restrict__ bev) {
    __shared__ int   hw_s[ZD][64];
    __shared__ float wgt_s[ZD][64];

    const int tx = threadIdx.x;          // 0..63 -> x
    const int cq = threadIdx.y;          // 0..3  -> channel quarter / z-slice
    const int x = blockIdx.x * 64 + tx;
    const int y = blockIdx.y;
    const int b = blockIdx.z;
    const float wx = (float)x * 0.8f + (-51.2f);
    const float wy = (float)y * 0.8f + (-51.2f);

    float acc[16];
#pragma unroll
    for (int m = 0; m < 16; ++m) acc[m] = 0.f;

    for (int n = 0; n < NC; ++n) {
        const int bn = b * NC + n;
        const float* E = e2c + bn * 12;
        const float* Km = Kmat + bn * 9;
        const float k00 = Km[0], k01 = Km[1], k02 = Km[2];
        const float k10 = Km[3], k11 = Km[4], k12 = Km[5];
        const float e02 = E[2], e12 = E[6], e22 = E[10];
        const float bx0 = E[0] * wx + E[1] * wy + E[3];
        const float bx1 = E[4] * wx + E[5] * wy + E[7];
        const float bx2 = E[8] * wx + E[9] * wy + E[11];

        // ---- projection phase: thread (tx,cq) owns z = cq and cq+4 ----
#pragma unroll
        for (int zz = 0; zz < 2; ++zz) {
            const int z = cq + zz * 4;
            if (z < ZD) {
                const float wz = -2.5f + (float)z;
                const float cx = bx0 + e02 * wz;
                const float cy = bx1 + e12 * wz;
                const float cz = bx2 + e22 * wz;
                const float zs = fmaxf(cz, 0.1f);
                const float rz = 1.0f / zs;         // IEEE divide
                const float xn = cx * rz;
                const float yn = cy * rz;
                const float fu = (k00 * xn + k01 * yn + k02) * 0.0625f;
                const float fv = (k10 * xn + k11 * yn + k12) * 0.0625f;
                const int bin = (int)(cz - 1.0f);   // trunc, matches astype(int32)
                const bool valid = (fu >= 0.f) & (fu < (float)W_IMG) &
                                   (fv >= 0.f) & (fv < (float)H_IMG) &
                                   (cz > 0.5f) & (bin >= 0) & (bin < D_BINS);
                int hw = -1;
                float wgt = 0.f;
                if (valid) {
                    int u = (int)fu;                // valid => in range
                    int v = (int)fv;
                    hw = v * W_IMG + u;
                    wgt = depth_g[((size_t)bn * HW + hw) * D_BINS + bin];
                }
                hw_s[z][tx] = hw;
                wgt_s[z][tx] = wgt;
            }
        }
        __syncthreads();

        // ---- accumulate phase: z ascending (same FMA order as baseline) ----
#pragma unroll
        for (int z = 0; z < ZD; ++z) {
            const int hw = hw_s[z][tx];       // 4 cq threads same addr: broadcast
            if (hw >= 0) {
                const float wgt = wgt_s[z][tx];
                const float4* fp =
                    (const float4*)(feat_ws + ((size_t)bn * HW + hw) * CO + cq * 16);
                float4 f0 = fp[0], f1 = fp[1], f2 = fp[2], f3 = fp[3];
                acc[0]  = fmaf(wgt, f0.x, acc[0]);
                acc[1]  = fmaf(wgt, f0.y, acc[1]);
                acc[2]  = fmaf(wgt, f0.z, acc[2]);
                acc[3]  = fmaf(wgt, f0.w, acc[3]);
                acc[4]  = fmaf(wgt, f1.x, acc[4]);
                acc[5]  = fmaf(wgt, f1.y, acc[5]);
                acc[6]  = fmaf(wgt, f1.z, acc[6]);
                acc[7]  = fmaf(wgt, f1.w, acc[7]);
                acc[8]  = fmaf(wgt, f2.x, acc[8]);
                acc[9]  = fmaf(wgt, f2.y, acc[9]);
                acc[10] = fmaf(wgt, f2.z, acc[10]);
                acc[11] = fmaf(wgt, f2.w, acc[11]);
                acc[12] = fmaf(wgt, f3.x, acc[12]);
                acc[13] = fmaf(wgt, f3.y, acc[13]);
                acc[14] = fmaf(wgt, f3.z, acc[14]);
                acc[15] = fmaf(wgt, f3.w, acc[15]);
            }
        }
        __syncthreads();   // LDS reused next n
    }
    // out[b][c][y][x], c = cq*16 + m; 64 lanes = consecutive x -> coalesced
    float* ob = bev + (((size_t)b * CO + cq * 16) * YD + y) * XD + x;
#pragma unroll
    for (int m = 0; m < 16; ++m) ob[(size_t)m * YD * XD] = acc[m];
}

extern "C" void kernel_launch(void* const* d_in, const int* in_sizes, int n_in,
                              void* d_out, int out_size, void* d_ws, size_t ws_size,
                              hipStream_t stream) {
    const float* img  = (const float*)d_in[0];  // (B,N,256,16,44)
    const float* c2e  = (const float*)d_in[1];  // (B,N,4,4)
    const float* Kmat = (const float*)d_in[2];  // (B,N,3,3)
    const float* wd   = (const float*)d_in[3];  // (123,256)
    const float* bd   = (const float*)d_in[4];  // (123,)
    float* bev = (float*)d_out;                         // (B,64,128,128)
    float* depth_out = bev + (size_t)NB * CO * YD * XD; // (B,N,16,44,59)
    float* feat_ws = (float*)d_ws;                      // NPIX*64 floats
    float* wt2 = feat_ws + (size_t)NPIX * CO;           // 128*256 floats
    float* e2c = wt2 + 128 * 256;                       // 24*12 floats

    k_pre<<<128, 256, 0, stream>>>(wd, c2e, wt2, e2c);
    k_head<<<256, 640, 0, stream>>>(img, wt2, bd, depth_out, feat_ws);
    k_splat<<<dim3(2, YD, NB), dim3(64, 4, 1), 0, stream>>>(e2c, Kmat, depth_out,
                                                            feat_ws, bev);
}